// Round 3
// baseline (887.211 us; speedup 1.0000x reference)
//
#include <hip/hip_runtime.h>

// Problem constants
#define Bn   32
#define Cc   512
#define CIc  256
#define Nsp  3136      // 56*56
#define EPSbn 1e-5f

typedef __attribute__((ext_vector_type(8))) short v8s;   // 8 x bf16 (4 VGPRs)
typedef __attribute__((ext_vector_type(4))) float v4f;   // MFMA accumulator

__device__ __forceinline__ unsigned short f2bf(float f) {
    unsigned int u = __builtin_bit_cast(unsigned int, f);
    u += 0x7fffu + ((u >> 16) & 1u);          // RNE
    return (unsigned short)(u >> 16);
}

__device__ __forceinline__ float bf2f(unsigned short u) {
    unsigned int x = ((unsigned int)u) << 16;
    return __builtin_bit_cast(float, x);
}

// async global->LDS, 16B per lane; LDS dest = wave-uniform base + lane*16
__device__ __forceinline__ void async16(const unsigned short* g, unsigned short* l) {
    __builtin_amdgcn_global_load_lds(
        (const __attribute__((address_space(1))) unsigned int*)g,
        (__attribute__((address_space(3))) unsigned int*)l, 16, 0, 0);
}

// Canonical bf16 MFMA GEMM:  O[gn][gm] = sum_k A[gm][k] * B[gn][k]
// A: [M][lda] bf16 (k-contig), B: [N][ldb] bf16 (k-contig).
// Block tile 128x128 (M x N), BK=32, 4 waves in 2x2, 4x4 16x16x32 MFMAs/wave.
// NCH: number of 128-wide N-chunks processed sequentially per block (grid y = N/128/NCH);
//      NCH>1 keeps the A-tile L2-resident across chunks (kills HBM re-fetch).
// EPI 0: bf16 store O[gn][gm] (* scale + optional biasN[bN_bs*b + gn])
// EPI 4: bf16 store of acc*scale + u1[b][gn]*w1[gm] + u2[gn]*w2[b][gm]  (rank-2 bias fix)
// EPI 5: out fp32 [c][n] = (acc + c0[b][gn] + x16res) * a1[gn] + a0[gn]  (fused BN apply)
template <int EPI, int NCH>
__global__ __launch_bounds__(256)
void mfma_gemm(const unsigned short* __restrict__ A, int lda, long a_bs,
               const unsigned short* __restrict__ B, int ldb, long b_bs,
               void* __restrict__ Out, int ldo, long o_bs,
               int K, float scale,
               const float* __restrict__ biasN, long bN_bs,
               const void* __restrict__ xres,
               const float* __restrict__ a10,
               const float* __restrict__ r2u1, const float* __restrict__ r2w1,
               const float* __restrict__ r2u2, const float* __restrict__ r2w2)
{
    __shared__ __align__(16) unsigned short As[128 * 32];  // [m][k] 8KB
    __shared__ __align__(16) unsigned short Bs[128 * 32];  // [n][k] 8KB

    const int tid  = threadIdx.x;
    const int w    = tid >> 6;
    const int lane = tid & 63;
    const int b    = blockIdx.z;
    const int m0   = blockIdx.x * 128;

    const unsigned short* Ab = A + (long)b * a_bs;
    const unsigned short* Bb = B + (long)b * b_bs;

    // staging map: chunk c = 2w+q covers LDS elems [c*512,(c+1)*512), lane elem = c*512+lane*8
    const int ldrow = 32 * w + (lane >> 2);
    const int ldk   = (lane & 3) * 8;
    unsigned short* lA0 = &As[(2 * w + 0) * 512];
    unsigned short* lA1 = &As[(2 * w + 1) * 512];
    unsigned short* lB0 = &Bs[(2 * w + 0) * 512];
    unsigned short* lB1 = &Bs[(2 * w + 1) * 512];
    const size_t aoff0 = (size_t)(m0 + ldrow) * lda + ldk;
    const size_t aoff1 = aoff0 + (size_t)16 * lda;

    const int wm = (w & 1) * 64;       // wave tile M offset
    const int wn = (w >> 1) * 64;      // wave tile N offset
    const int fr = lane & 15;
    const int fk = (lane >> 4) * 8;

    // C/D layout: col(n-role)=lane&15, row(m-role)=quad*4+reg -> 4 consecutive m per lane
    const int em = wm + ((lane >> 4) << 2);
    const int en = wn + fr;

    for (int nc = 0; nc < NCH; ++nc) {
        const int n0 = (NCH == 1 ? (int)blockIdx.y : nc) * 128;
        const size_t boff0 = (size_t)(n0 + ldrow) * ldb + ldk;
        const size_t boff1 = boff0 + (size_t)16 * ldb;

        v4f acc[4][4] = {};

        for (int k0 = 0; k0 < K; k0 += 32) {
            __syncthreads();                        // previous tile's ds_reads done
            async16(Ab + aoff0 + k0, lA0);
            async16(Ab + aoff1 + k0, lA1);
            async16(Bb + boff0 + k0, lB0);
            async16(Bb + boff1 + k0, lB1);
            __syncthreads();                        // drains vmcnt -> LDS valid

            v8s af[4], bf[4];
#pragma unroll
            for (int i = 0; i < 4; ++i)
                af[i] = *(const v8s*)&As[(wm + i * 16 + fr) * 32 + fk];
#pragma unroll
            for (int j = 0; j < 4; ++j)
                bf[j] = *(const v8s*)&Bs[(wn + j * 16 + fr) * 32 + fk];
#pragma unroll
            for (int i = 0; i < 4; ++i)
#pragma unroll
                for (int j = 0; j < 4; ++j)
                    acc[i][j] = __builtin_amdgcn_mfma_f32_16x16x32_bf16(af[i], bf[j], acc[i][j], 0, 0, 0);
        }

        if constexpr (EPI == 0) {
            unsigned short* O = (unsigned short*)Out;
#pragma unroll
            for (int j = 0; j < 4; ++j) {
                const int gn = n0 + en + j * 16;
                const float bN = biasN ? biasN[bN_bs * b + gn] : 0.0f;
                unsigned short* orow = O + (long)b * o_bs + (size_t)gn * ldo + m0 + em;
#pragma unroll
                for (int i = 0; i < 4; ++i) {
                    ushort4 o4;
                    o4.x = f2bf(acc[i][j].x * scale + bN);
                    o4.y = f2bf(acc[i][j].y * scale + bN);
                    o4.z = f2bf(acc[i][j].z * scale + bN);
                    o4.w = f2bf(acc[i][j].w * scale + bN);
                    *(ushort4*)&orow[i * 16] = o4;
                }
            }
        } else if constexpr (EPI == 4) {
            unsigned short* O = (unsigned short*)Out;
#pragma unroll
            for (int j = 0; j < 4; ++j) {
                const int gn = n0 + en + j * 16;                 // f index
                const float uu1 = r2u1[(size_t)b * Cc + gn];
                const float uu2 = r2u2[gn];
                unsigned short* orow = O + (long)b * o_bs + (size_t)gn * ldo + m0 + em;
#pragma unroll
                for (int i = 0; i < 4; ++i) {
                    const int e0 = m0 + em + i * 16;             // e index base
                    const float4 w1v = *(const float4*)&r2w1[e0];
                    const float4 w2v = *(const float4*)&r2w2[(size_t)b * Cc + e0];
                    ushort4 o4;
                    o4.x = f2bf(acc[i][j].x * scale + uu1 * w1v.x + uu2 * w2v.x);
                    o4.y = f2bf(acc[i][j].y * scale + uu1 * w1v.y + uu2 * w2v.y);
                    o4.z = f2bf(acc[i][j].z * scale + uu1 * w1v.z + uu2 * w2v.z);
                    o4.w = f2bf(acc[i][j].w * scale + uu1 * w1v.w + uu2 * w2v.w);
                    *(ushort4*)&orow[i * 16] = o4;
                }
            }
        } else {  // EPI == 5: fused BN output, fp32
            float* O = (float*)Out;
            const unsigned short* xr16 = (const unsigned short*)xres;
#pragma unroll
            for (int j = 0; j < 4; ++j) {
                const int gc = n0 + en + j * 16;
                const float a1 = a10[gc];
                const float a0 = a10[Cc + gc];
                const float cc0 = biasN[bN_bs * b + gc];
                const unsigned short* xrow = xr16 + (size_t)b * Cc * Nsp + (size_t)gc * Nsp;
                float* orow = O + (long)b * o_bs + (size_t)gc * (size_t)ldo;
#pragma unroll
                for (int i = 0; i < 4; ++i) {
                    const int gsp = m0 + em + i * 16;
                    if (gsp < Nsp) {
                        const ushort4 xr = *(const ushort4*)&xrow[gsp];
                        float4 o;
                        o.x = (acc[i][j].x + cc0 + bf2f(xr.x)) * a1 + a0;
                        o.y = (acc[i][j].y + cc0 + bf2f(xr.y)) * a1 + a0;
                        o.z = (acc[i][j].z + cc0 + bf2f(xr.z)) * a1 + a0;
                        o.w = (acc[i][j].w + cc0 + bf2f(xr.w)) * a1 + a0;
                        *(float4*)&orow[gsp] = o;
                    }
                }
            }
        }
    }
}

// x fp32 [b][c][n] -> xT bf16 [b][n][c] AND x16 bf16 [b][c][n]; accumulates
// per-channel r[b][c] = sum_n x16, p[b][c] = sum_n x16^2 (fp32, of the ROUNDED values,
// so the algebraic BN stats are consistent with the bf16 GEMM inputs).
__global__ __launch_bounds__(256)
void cast_transpose(const float* __restrict__ x, unsigned short* __restrict__ xT,
                    unsigned short* __restrict__ x16, float* __restrict__ r,
                    float* __restrict__ p)
{
    __shared__ float tile[64][65];
    const int b  = blockIdx.z;
    const int n0 = blockIdx.x * 64;
    const int c0 = blockIdx.y * 64;
    const float* xb = x + (size_t)b * Cc * Nsp;
    unsigned short* x16b = x16 + (size_t)b * Cc * Nsp;
    const int t = threadIdx.x;
    const int tr  = t >> 4;            // 0..15
    const int tc4 = (t & 15) * 4;
    float rs[4], ps[4];
#pragma unroll
    for (int i = 0; i < 4; ++i) {
        const int c = tr + i * 16;
        const float4 v = *(const float4*)&xb[(size_t)(c0 + c) * Nsp + n0 + tc4];
        tile[tc4 + 0][c] = v.x;
        tile[tc4 + 1][c] = v.y;
        tile[tc4 + 2][c] = v.z;
        tile[tc4 + 3][c] = v.w;
        ushort4 s;
        s.x = f2bf(v.x); s.y = f2bf(v.y); s.z = f2bf(v.z); s.w = f2bf(v.w);
        *(ushort4*)&x16b[(size_t)(c0 + c) * Nsp + n0 + tc4] = s;
        const float b0 = bf2f(s.x), b1 = bf2f(s.y), b2 = bf2f(s.z), b3 = bf2f(s.w);
        rs[i] = b0 + b1 + b2 + b3;
        ps[i] = b0 * b0 + b1 * b1 + b2 * b2 + b3 * b3;
    }
    // reduce over the 16 lanes sharing a channel (t&15 groups, same wave)
#pragma unroll
    for (int i = 0; i < 4; ++i) {
#pragma unroll
        for (int off = 8; off; off >>= 1) {
            rs[i] += __shfl_down(rs[i], off, 16);
            ps[i] += __shfl_down(ps[i], off, 16);
        }
    }
    if ((t & 15) == 0) {
#pragma unroll
        for (int i = 0; i < 4; ++i) {
            atomicAdd(&r[(size_t)b * Cc + c0 + tr + i * 16], rs[i]);
            atomicAdd(&p[(size_t)b * Cc + c0 + tr + i * 16], ps[i]);
        }
    }
    __syncthreads();
    unsigned short* xo = xT + (size_t)b * Nsp * Cc;
#pragma unroll
    for (int i = 0; i < 4; ++i) {
        const int n = tr + i * 16;
        ushort4 o;
        o.x = f2bf(tile[n][tc4 + 0]);
        o.y = f2bf(tile[n][tc4 + 1]);
        o.z = f2bf(tile[n][tc4 + 2]);
        o.w = f2bf(tile[n][tc4 + 3]);
        *(ushort4*)&xo[(size_t)(n0 + n) * Cc + c0 + tc4] = o;
    }
}

__global__ void cast_w(const float* __restrict__ src, unsigned short* __restrict__ dst, int n)
{
    const int i = (blockIdx.x * 256 + threadIdx.x) * 4;
    if (i < n) {
        const float4 v = *(const float4*)&src[i];
        ushort4 o;
        o.x = f2bf(v.x); o.y = f2bf(v.y); o.z = f2bf(v.z); o.w = f2bf(v.w);
        *(ushort4*)&dst[i] = o;
    }
}

// src fp32 [256][512] -> dst bf16 [512][256] transposed (tiny)
__global__ void cast_wT(const float* __restrict__ src, unsigned short* __restrict__ dst)
{
    const int c = blockIdx.x;          // 512
    const int d = threadIdx.x;         // 256
    dst[(size_t)c * CIc + d] = f2bf(src[(size_t)d * Cc + c]);
}

// Batch-independent bias vectors: w1 = g_w^T ph_b, q = ph_w^T g_b, u2 = W_w th_b,
// pbgb = ph_b . g_b   (all zero when biases are zero)
__global__ void k_vec1(const float* __restrict__ g_w, const float* __restrict__ ph_w,
                       const float* __restrict__ W_w, const float* __restrict__ th_b,
                       const float* __restrict__ ph_b, const float* __restrict__ g_b,
                       float* __restrict__ w1, float* __restrict__ q,
                       float* __restrict__ u2, float* __restrict__ pbgb)
{
    const int t = threadIdx.x;  // 512
    float a = 0.f, bq = 0.f;
    for (int d = 0; d < CIc; ++d) {
        a  += g_w[(size_t)d * Cc + t] * ph_b[d];
        bq += ph_w[(size_t)d * Cc + t] * g_b[d];
    }
    w1[t] = a; q[t] = bq;
    float u = 0.f;
    for (int c = 0; c < CIc; ++c) u += W_w[(size_t)t * CIc + c] * th_b[c];
    u2[t] = u;
    if (t == 0) {
        float s = 0.f;
        for (int d = 0; d < CIc; ++d) s += ph_b[d] * g_b[d];
        *pbgb = s;
    }
}

// Per-batch bias vectors: u1 = WT r / N, w2 = PG^T r / N + w1,
// c0 = W_w * fgb + W_b where fgb = (Th(Sq) + pbgb*(Th r) + (r.q) th_b)/N + pbgb*th_b
__global__ void k_vecb(const unsigned short* __restrict__ S, const unsigned short* __restrict__ WT,
                       const unsigned short* __restrict__ PGt, const float* __restrict__ r,
                       const float* __restrict__ w1, const float* __restrict__ q,
                       const float* __restrict__ pbgb,
                       const float* __restrict__ th_w, const float* __restrict__ th_b,
                       const float* __restrict__ W_w, const float* __restrict__ W_b,
                       float* __restrict__ u1, float* __restrict__ w2, float* __restrict__ c0)
{
    const int b = blockIdx.x, t = threadIdx.x;   // 512 threads
    __shared__ float sq[Cc];
    __shared__ float fgb[CIc];
    __shared__ float s_rq;
    const float invN = 1.0f / (float)Nsp;
    const float* rb = r + (size_t)b * Cc;

    float aq = 0.f;
    const unsigned short* Sr = S + (size_t)b * Cc * Cc + (size_t)t * Cc;
    for (int c2 = 0; c2 < Cc; ++c2) aq += bf2f(Sr[c2]) * q[c2];
    sq[t] = aq;

    float a1 = 0.f;
    const unsigned short* WTr = WT + (size_t)t * Cc;
    for (int c1 = 0; c1 < Cc; ++c1) a1 += bf2f(WTr[c1]) * rb[c1];
    u1[(size_t)b * Cc + t] = a1 * invN;

    float a2 = 0.f;
    const unsigned short* PGr = PGt + (size_t)t * Cc;
    for (int c2 = 0; c2 < Cc; ++c2) a2 += bf2f(PGr[c2]) * rb[c2];
    w2[(size_t)b * Cc + t] = a2 * invN + w1[t];

    if (t == 0) {
        float s = 0.f;
        for (int c2 = 0; c2 < Cc; ++c2) s += rb[c2] * q[c2];
        s_rq = s;
    }
    __syncthreads();
    if (t < CIc) {
        float ts = 0.f, tr2 = 0.f;
        const float* thr = th_w + (size_t)t * Cc;
        for (int c1 = 0; c1 < Cc; ++c1) { ts += thr[c1] * sq[c1]; tr2 += thr[c1] * rb[c1]; }
        const float pg = *pbgb;
        fgb[t] = (ts + pg * tr2 + s_rq * th_b[t]) * invN + pg * th_b[t];
    }
    __syncthreads();
    float cacc = 0.f;
    const float* Wr = W_w + (size_t)t * CIc;
    for (int d = 0; d < CIc; ++d) cacc += Wr[d] * fgb[d];
    c0[(size_t)b * Cc + t] = cacc + W_b[t];
}

// Algebraic BN stats from S/Afull/AS (z never materialized):
//   sum_n z[f][n]   = (A r)[f] + r[f] + N c0
//   sum_n z[f][n]^2 = diag(A S A^T)[f] + 2 c0 (A r)[f] + N c0^2
//                     + 2 AS[f][f] + 2 c0 r[f] + p[f]
// One wave per (b,f) row; rows are 512 bf16 = 1KB coalesced per operand.
__global__ __launch_bounds__(256)
void k_stats(const unsigned short* __restrict__ Afull, const unsigned short* __restrict__ AS,
             const float* __restrict__ r, const float* __restrict__ p,
             const float* __restrict__ c0, float* __restrict__ stats)
{
    const int b = blockIdx.x;
    const int f = blockIdx.y * 4 + (threadIdx.x >> 6);
    const int lane = threadIdx.x & 63;
    const size_t row = ((size_t)b * Cc + f) * Cc;
    const v8s av = *(const v8s*)(Afull + row + lane * 8);
    const v8s sv = *(const v8s*)(AS + row + lane * 8);
    const float* rb = r + (size_t)b * Cc + lane * 8;
    float d1 = 0.f, ar = 0.f;
#pragma unroll
    for (int k = 0; k < 8; ++k) {
        const float a = bf2f((unsigned short)av[k]);
        d1 += a * bf2f((unsigned short)sv[k]);
        ar += a * rb[k];
    }
#pragma unroll
    for (int off = 32; off; off >>= 1) {
        d1 += __shfl_down(d1, off);
        ar += __shfl_down(ar, off);
    }
    if (lane == 0) {
        const float cc   = c0[(size_t)b * Cc + f];
        const float rf   = r[(size_t)b * Cc + f];
        const float pf   = p[(size_t)b * Cc + f];
        const float asff = bf2f(AS[row + f]);
        const float sum = ar + rf + (float)Nsp * cc;
        const float ss  = d1 + 2.f * cc * ar + (float)Nsp * cc * cc
                        + 2.f * asff + 2.f * cc * rf + pf;
        atomicAdd(&stats[f], sum);
        atomicAdd(&stats[Cc + f], ss);
    }
}

__global__ void finalize_stats(const float* __restrict__ stats,
                               const float* __restrict__ gamma, const float* __restrict__ beta,
                               float* __restrict__ a10)
{
    const int c = threadIdx.x;  // 512
    const float inv = 1.0f / (float)((long)Bn * Nsp);
    const float mean = stats[c] * inv;
    const float var  = stats[Cc + c] * inv - mean * mean;
    const float a1 = rsqrtf(var + EPSbn) * gamma[c];
    a10[c] = a1;
    a10[Cc + c] = beta[c] - mean * a1;
}

extern "C" void kernel_launch(void* const* d_in, const int* in_sizes, int n_in,
                              void* d_out, int out_size, void* d_ws, size_t ws_size,
                              hipStream_t stream)
{
    const float* x     = (const float*)d_in[0];
    const float* g_w   = (const float*)d_in[1];
    const float* g_b   = (const float*)d_in[2];
    const float* th_w  = (const float*)d_in[3];
    const float* th_b  = (const float*)d_in[4];
    const float* ph_w  = (const float*)d_in[5];
    const float* ph_b  = (const float*)d_in[6];
    const float* W_w   = (const float*)d_in[7];
    const float* W_b   = (const float*)d_in[8];
    const float* gamma = (const float*)d_in[9];
    const float* beta  = (const float*)d_in[10];
    float* out = (float*)d_out;

    // Pipeline (linear collapse + algebraic BN stats => single pass over spatial data):
    //   S_b = x16 x16^T ;  Rt = (S PG)^T ;  A_b = WT Rt^T / N + rank2 ;  AS = A S
    //   stats from {AS, A, r, p, c0} closed-form ;  out = (A x16 + x16 + c0) * a1 + a0
    unsigned short* xT   = (unsigned short*)d_ws;                       // [32][3136][512] (+64 rows pad)
    unsigned short* x16  = xT + (size_t)Bn * Nsp * Cc + 64 * Cc;        // [32][512][3136]
    unsigned short* S    = x16 + (size_t)Bn * Cc * Nsp;                 // [32][512][512]
    unsigned short* R1   = S + (size_t)Bn * Cc * Cc;                    // Rt, then AS
    unsigned short* R2   = R1 + (size_t)Bn * Cc * Cc;                   // Afull
    unsigned short* WT   = R2 + (size_t)Bn * Cc * Cc;
    unsigned short* PGt  = WT + (size_t)Cc * Cc;
    unsigned short* thwT = PGt + (size_t)Cc * Cc;
    unsigned short* phwT = thwT + (size_t)Cc * CIc;
    unsigned short* gwT  = phwT + (size_t)Cc * CIc;
    unsigned short* Ww16 = gwT + (size_t)Cc * CIc;
    float* r    = (float*)(Ww16 + (size_t)Cc * CIc);
    float* p    = r + Bn * Cc;
    float* w1   = p + Bn * Cc;
    float* q    = w1 + Cc;
    float* u2v  = q + Cc;
    float* pbgb = u2v + Cc;
    float* u1v  = pbgb + 4;
    float* w2v  = u1v + Bn * Cc;
    float* c0   = w2v + Bn * Cc;
    float* stats = c0 + Bn * Cc;
    float* a10   = stats + 2 * Cc;

    unsigned short* Rt    = R1;
    unsigned short* Afull = R2;
    unsigned short* AS    = R1;    // Rt dead once Afull exists

    hipMemsetAsync(stats, 0, 2 * Cc * sizeof(float), stream);
    hipMemsetAsync(r, 0, 2 * (size_t)Bn * Cc * sizeof(float), stream);  // r and p

    const dim3 blk(256);
    const long xT_bs  = (long)Nsp * Cc;
    const long x16_bs = (long)Cc * Nsp;
    const long sq_bs  = (long)Cc * Cc;   // 512x512 per-batch matrices

    cast_transpose<<<dim3(49, 8, Bn), blk, 0, stream>>>(x, xT, x16, r, p);
    cast_w<<<dim3(128), blk, 0, stream>>>(W_w, Ww16, Cc * CIc);
    cast_wT<<<dim3(Cc), dim3(CIc), 0, stream>>>(th_w, thwT);
    cast_wT<<<dim3(Cc), dim3(CIc), 0, stream>>>(ph_w, phwT);
    cast_wT<<<dim3(Cc), dim3(CIc), 0, stream>>>(g_w, gwT);
    k_vec1<<<dim3(1), dim3(Cc), 0, stream>>>(g_w, ph_w, W_w, th_b, ph_b, g_b, w1, q, u2v, pbgb);

    // WT[f][c1] = sum_c th_w[c][c1] W_w[f][c]   (batch-indep)
    mfma_gemm<0, 1><<<dim3(4, 4, 1), blk, 0, stream>>>(
        thwT, CIc, 0, Ww16, CIc, 0, WT, Cc, 0, CIc, 1.0f,
        nullptr, 0, nullptr, nullptr, nullptr, nullptr, nullptr, nullptr);
    // PGt[e][c2] = sum_d ph_w[d][c2] g_w[d][e]
    mfma_gemm<0, 1><<<dim3(4, 4, 1), blk, 0, stream>>>(
        phwT, CIc, 0, gwT, CIc, 0, PGt, Cc, 0, CIc, 1.0f,
        nullptr, 0, nullptr, nullptr, nullptr, nullptr, nullptr, nullptr);
    // S[c2][c1] = sum_n x16[c1][n] x16[c2][n]   (symmetric)
    mfma_gemm<0, 1><<<dim3(4, 4, Bn), blk, 0, stream>>>(
        x16, Nsp, x16_bs, x16, Nsp, x16_bs, S, Cc, sq_bs, Nsp, 1.0f,
        nullptr, 0, nullptr, nullptr, nullptr, nullptr, nullptr, nullptr);
    // Rt[e][c1] = sum_c2 S[c1][c2] PGt[e][c2]
    mfma_gemm<0, 1><<<dim3(4, 4, Bn), blk, 0, stream>>>(
        S, Cc, sq_bs, PGt, Cc, 0, Rt, Cc, sq_bs, Cc, 1.0f,
        nullptr, 0, nullptr, nullptr, nullptr, nullptr, nullptr, nullptr);
    // per-batch bias vectors (needs S, WT, PGt, r)
    k_vecb<<<dim3(Bn), dim3(Cc), 0, stream>>>(S, WT, PGt, r, w1, q, pbgb,
                                              th_w, th_b, W_w, W_b, u1v, w2v, c0);
    // Afull[f][e] = (1/N) sum_c1 Rt[e][c1] WT[f][c1] + u1 w1^T + u2 w2^T
    mfma_gemm<4, 1><<<dim3(4, 4, Bn), blk, 0, stream>>>(
        Rt, Cc, sq_bs, WT, Cc, 0, Afull, Cc, sq_bs, Cc, 1.0f / (float)Nsp,
        nullptr, 0, nullptr, nullptr, u1v, w1, u2v, w2v);
    // AS[f][c1] = sum_e S[c1][e] Afull[f][e]   (= (A S)[f][c1]; Rt's space reused)
    mfma_gemm<0, 1><<<dim3(4, 4, Bn), blk, 0, stream>>>(
        S, Cc, sq_bs, Afull, Cc, sq_bs, AS, Cc, sq_bs, Cc, 1.0f,
        nullptr, 0, nullptr, nullptr, nullptr, nullptr, nullptr, nullptr);
    k_stats<<<dim3(Bn, 128), blk, 0, stream>>>(Afull, AS, r, p, c0, stats);
    finalize_stats<<<dim3(1), dim3(Cc), 0, stream>>>(stats, gamma, beta, a10);
    // out[f][n] = (sum_e Afull[f][e] xT[n][e] + c0[b][f] + x16) * a1[f] + a0[f]
    // NCH=4: one block per spatial tile walks all 4 channel chunks (A-tile L2-resident)
    mfma_gemm<5, 4><<<dim3(25, 1, Bn), blk, 0, stream>>>(
        xT, Cc, xT_bs, Afull, Cc, sq_bs, out, Nsp, (long)Cc * Nsp, Cc, 1.0f,
        c0, Cc, x16, a10, nullptr, nullptr, nullptr, nullptr);
}